// Round 1
// baseline (21678.616 us; speedup 1.0000x reference)
//
#include <hip/hip_runtime.h>

#define NB 64
#define NS 512
#define NI 512
#define NH 1024

typedef __attribute__((ext_vector_type(8))) short bf16x8;
typedef __attribute__((ext_vector_type(4))) float f32x4;

// ---- LDS layout (bytes). Rows padded +16B -> bank-conflict-free B-frag reads.
#define PW   2064          // padded row stride, K=1024 matrices
#define PW0  1040          // padded row stride, K=512 (Wx0)
#define OFF_WH0 0
#define OFF_WX1 33024
#define OFF_WH1 66048
#define OFF_WX0 99072
#define OFF_PB  115712     // 16 tiles * 256 f32 = 16 KB partial buffer
#define OFF_BIAS 132096    // 32 f32 combined biases
#define SMEM_BYTES 132224

// ---- workspace layout
#define WS_H0 4096                    // two 128KB bf16 buffers [64][1024]
#define WS_H1 (4096 + 2*131072)
#define WS_ZERO_BYTES (4096 + 4*131072)

// ---- output layout (fp32): y [64,512,1024]; h_n [2,64,1024]; c_n [2,64,1024]
#define OUT_HN 33554432
#define OUT_CN (33554432 + 131072)

__device__ __forceinline__ unsigned short f2bf(float f) {
  unsigned u = __float_as_uint(f);
  return (unsigned short)((u + 0x7fffu + ((u >> 16) & 1u)) >> 16);
}
__device__ __forceinline__ float sigm(float v)  { return 1.f / (1.f + __expf(-v)); }
__device__ __forceinline__ float tanha(float v) { return 1.f - 2.f / (__expf(2.f * v) + 1.f); }

// One block per CU. Each block owns hidden units [4*cu, 4*cu+4) of BOTH layers:
// 16 gate-columns per matrix (i,f,o,g x 4 units), weights bf16 in LDS.
// Phase t: layer0 computes step t, layer1 computes step t-1 (1-step pipeline)
// -> exactly one grid barrier per phase.
__global__ __launch_bounds__(512, 2) void lstm2(
    const float* __restrict__ x,
    const float* __restrict__ Wx0, const float* __restrict__ Wh0,
    const float* __restrict__ bx0, const float* __restrict__ bh0,
    const float* __restrict__ Wx1, const float* __restrict__ Wh1,
    const float* __restrict__ bx1, const float* __restrict__ bh1,
    float* __restrict__ out, char* __restrict__ ws)
{
  extern __shared__ char smem[];
  float* PB   = (float*)(smem + OFF_PB);
  float* BIAS = (float*)(smem + OFF_BIAS);

  const int tid = threadIdx.x;
  const int cu  = blockIdx.x;

  int* cnt = (int*)ws;
  unsigned short* h0b0 = (unsigned short*)(ws + WS_H0);
  unsigned short* h0b1 = (unsigned short*)(ws + WS_H0 + 131072);
  unsigned short* h1b0 = (unsigned short*)(ws + WS_H1);
  unsigned short* h1b1 = (unsigned short*)(ws + WS_H1 + 131072);

  // ---- one-time: stage this CU's weight slices into LDS as bf16 ----
  for (int idx = tid; idx < 16 * 1024; idx += 512) {
    const int s = idx >> 10, k = idx & 1023;            // s = gate*4 + unit
    const int j = (s >> 2) * 1024 + cu * 4 + (s & 3);   // global row in [4096]
    *(unsigned short*)(smem + OFF_WH0 + s * PW + 2 * k) = f2bf(Wh0[j * 1024 + k]);
    *(unsigned short*)(smem + OFF_WX1 + s * PW + 2 * k) = f2bf(Wx1[j * 1024 + k]);
    *(unsigned short*)(smem + OFF_WH1 + s * PW + 2 * k) = f2bf(Wh1[j * 1024 + k]);
  }
  for (int idx = tid; idx < 16 * 512; idx += 512) {
    const int s = idx >> 9, k = idx & 511;
    const int j = (s >> 2) * 1024 + cu * 4 + (s & 3);
    *(unsigned short*)(smem + OFF_WX0 + s * PW0 + 2 * k) = f2bf(Wx0[j * 512 + k]);
  }
  if (tid < 32) {
    const int L = tid >> 4, s = tid & 15;
    const int j = (s >> 2) * 1024 + cu * 4 + (s & 3);
    BIAS[tid] = (L == 0) ? (bx0[j] + bh0[j]) : (bx1[j] + bh1[j]);
  }
  __syncthreads();

  // wave roles: wid = m(0..3) | role<<2 ; role0: h0 -> {C0+=h0*Wh0, C1+=h0*Wx1}
  //                                      role1: x -> C0+=x*Wx0 ; h1 -> C1+=h1*Wh1
  const int lane = tid & 63, wid = tid >> 6;
  const int m = wid & 3, role = wid >> 2;
  const int arow = lane & 15, agrp = lane >> 4;   // A: row=lane&15, k-group=lane>>4
  const int bcol = lane & 15;                     // B: col=lane&15
  const int Ar = 16 * m + arow;
  const int bofsK = bcol * PW  + agrp * 16;
  const int bofs0 = bcol * PW0 + agrp * 16;

  // elementwise ownership: thread -> (layer, unit, batch); c-state in a register
  const int eL = tid >> 8, eu = tid & 3, eb = (tid >> 2) & 63;
  const int erow = eb & 15, emt = eb >> 4;
  const int nglob = cu * 4 + eu;
  float cst = 0.f;
  int bar_dead = 0;

  for (int t = 0; t <= NS; ++t) {
    f32x4 c0 = {0.f, 0.f, 0.f, 0.f};
    f32x4 c1 = {0.f, 0.f, 0.f, 0.f};
    const unsigned short* h0_rd = ((t & 1) == 0) ? h0b1 : h0b0;  // h0(t-1)
    const unsigned short* h1_rd = (t & 1) ? h1b1 : h1b0;         // h1(t-2)

    if (role == 0) {
      const char* ap  = (const char*)h0_rd + Ar * 2048 + agrp * 16;
      const char* b0p = smem + OFF_WH0 + bofsK;
      const char* b1p = smem + OFF_WX1 + bofsK;
#pragma unroll 8
      for (int ks = 0; ks < 32; ++ks) {
        bf16x8 a  = *(const bf16x8*)(ap + ks * 64);
        bf16x8 w0 = *(const bf16x8*)(b0p + ks * 64);
        bf16x8 w1 = *(const bf16x8*)(b1p + ks * 64);
        c0 = __builtin_amdgcn_mfma_f32_16x16x32_bf16(a, w0, c0, 0, 0, 0);
        c1 = __builtin_amdgcn_mfma_f32_16x16x32_bf16(a, w1, c1, 0, 0, 0);
      }
    } else {
      if (t < NS) {
        const float* xp = x + (Ar * NS + t) * NI + agrp * 8;
        const char* b0p = smem + OFF_WX0 + bofs0;
#pragma unroll 4
        for (int ks = 0; ks < 16; ++ks) {
          f32x4 f0 = *(const f32x4*)(xp + ks * 32);
          f32x4 f1 = *(const f32x4*)(xp + ks * 32 + 4);
          bf16x8 a;
          a[0] = (short)f2bf(f0[0]); a[1] = (short)f2bf(f0[1]);
          a[2] = (short)f2bf(f0[2]); a[3] = (short)f2bf(f0[3]);
          a[4] = (short)f2bf(f1[0]); a[5] = (short)f2bf(f1[1]);
          a[6] = (short)f2bf(f1[2]); a[7] = (short)f2bf(f1[3]);
          bf16x8 w0 = *(const bf16x8*)(b0p + ks * 64);
          c0 = __builtin_amdgcn_mfma_f32_16x16x32_bf16(a, w0, c0, 0, 0, 0);
        }
      }
      const char* ap  = (const char*)h1_rd + Ar * 2048 + agrp * 16;
      const char* b1p = smem + OFF_WH1 + bofsK;
#pragma unroll 8
      for (int ks = 0; ks < 32; ++ks) {
        bf16x8 a  = *(const bf16x8*)(ap + ks * 64);
        bf16x8 w1 = *(const bf16x8*)(b1p + ks * 64);
        c1 = __builtin_amdgcn_mfma_f32_16x16x32_bf16(a, w1, c1, 0, 0, 0);
      }
    }

    // dump partial tiles: D layout col=lane&15, row=(lane>>4)*4+r  [m89]
    {
      const int ti0 = ((m << 1) | role) << 1;
      float* p0 = PB + ti0 * 256;
      float* p1 = PB + (ti0 + 1) * 256;
      const int rb = agrp * 4;
#pragma unroll
      for (int r = 0; r < 4; ++r) {
        p0[(rb + r) * 16 + bcol] = c0[r];
        p1[(rb + r) * 16 + bcol] = c1[r];
      }
    }
    __syncthreads();

    const bool act = (eL == 0) ? (t < NS) : (t >= 1);
    if (act) {
      const int tiA = (emt << 2) | eL;        // role0 contribution
      const int tiB = (emt << 2) | 2 | eL;    // role1 contribution
      const float* pA = PB + tiA * 256 + erow * 16;
      const float* pB = PB + tiB * 256 + erow * 16;
      const float* bi = BIAS + eL * 16;
      float gi = pA[eu]      + pB[eu]      + bi[eu];
      float gf = pA[eu + 4]  + pB[eu + 4]  + bi[eu + 4];
      float go = pA[eu + 8]  + pB[eu + 8]  + bi[eu + 8];
      float gg = pA[eu + 12] + pB[eu + 12] + bi[eu + 12];
      float cn = sigm(gf) * cst + sigm(gi) * tanha(gg);
      float hn = sigm(go) * tanha(cn);
      cst = cn;
      const unsigned short hb = f2bf(hn);
      if (eL == 0) {
        unsigned short* wr = (t & 1) ? h0b1 : h0b0;      // h0(t) -> buf t&1
        wr[eb * NH + nglob] = hb;
        if (t == NS - 1) {
          out[OUT_HN + eb * NH + nglob] = hn;
          out[OUT_CN + eb * NH + nglob] = cn;
        }
      } else {
        unsigned short* wr = (t & 1) ? h1b0 : h1b1;      // h1(t-1) -> buf (t-1)&1
        wr[eb * NH + nglob] = hb;
        out[(eb * NS + (t - 1)) * NH + nglob] = hn;
        if (t == NS) {
          out[OUT_HN + 65536 + eb * NH + nglob] = hn;
          out[OUT_CN + 65536 + eb * NH + nglob] = cn;
        }
      }
    }

    if (t == NS) break;

    // ---- grid barrier: monotonic counter, device-scope; timeout -> no hang ----
    __syncthreads();
    if (tid == 0) {
      __threadfence();  // wb L2 (h writes) before signaling across XCDs
      __hip_atomic_fetch_add(cnt, 1, __ATOMIC_RELEASE, __HIP_MEMORY_SCOPE_AGENT);
      if (!bar_dead) {
        const int target = 256 * (t + 1);
        int spins = 0;
        while (__hip_atomic_load(cnt, __ATOMIC_ACQUIRE, __HIP_MEMORY_SCOPE_AGENT) < target) {
          __builtin_amdgcn_s_sleep(2);
          if (++spins > (1 << 21)) { bar_dead = 1; break; }
        }
      }
      __threadfence();  // inv L1/L2 so next phase's h reads are fresh
    }
    __syncthreads();
  }
}

extern "C" void kernel_launch(void* const* d_in, const int* in_sizes, int n_in,
                              void* d_out, int out_size, void* d_ws, size_t ws_size,
                              hipStream_t stream) {
  const float* x   = (const float*)d_in[0];
  const float* Wx0 = (const float*)d_in[1];
  const float* Wh0 = (const float*)d_in[2];
  const float* bx0 = (const float*)d_in[3];
  const float* bh0 = (const float*)d_in[4];
  const float* Wx1 = (const float*)d_in[5];
  const float* Wh1 = (const float*)d_in[6];
  const float* bx1 = (const float*)d_in[7];
  const float* bh1 = (const float*)d_in[8];
  float* out = (float*)d_out;
  char* ws = (char*)d_ws;

  (void)hipFuncSetAttribute((const void*)lstm2,
                            hipFuncAttributeMaxDynamicSharedMemorySize, SMEM_BYTES);
  (void)hipMemsetAsync(ws, 0, WS_ZERO_BYTES, stream);  // zero barrier cnt + h ping-pong bufs
  hipLaunchKernelGGL(lstm2, dim3(256), dim3(512), SMEM_BYTES, stream,
                     x, Wx0, Wh0, bx0, bh0, Wx1, Wh1, bx1, bh1, out, ws);
}

// Round 2
// 11850.345 us; speedup vs baseline: 1.8294x; 1.8294x over previous
//
#include <hip/hip_runtime.h>

#define NB 64
#define NS 512
#define NI 512
#define NH 1024

typedef __attribute__((ext_vector_type(8))) short bf16x8;
typedef __attribute__((ext_vector_type(4))) float f32x4;
typedef __attribute__((ext_vector_type(4))) unsigned short u16x4;
typedef unsigned long long u64;

// ---- LDS layout (bytes). Rows padded +16B -> bank-conflict-free B-frag reads.
#define PW   2064          // padded row stride, K=1024 matrices
#define PW0  1040          // padded row stride, K=512 (Wx0)
#define OFF_WH0 0
#define OFF_WX1 33024
#define OFF_WH1 66048
#define OFF_WX0 99072
#define OFF_PB  115712     // 16 tiles * 256 f32 = 16 KB partial buffer
#define OFF_BIAS 132096    // 32 f32 combined biases
#define SMEM_BYTES 132224

// ---- workspace layout
#define WS_H0 4096                    // two 128KB bf16 buffers [64][1024]
#define WS_H1 (4096 + 2*131072)
#define WS_ZERO_BYTES (4096 + 4*131072)
#define WS_XB (1u << 20)              // bf16 x, time-major [512][64][512] = 33.55 MB
#define WS_XB_NEED (WS_XB + 2u*NS*NB*NI)

// ---- output layout (fp32): y [64,512,1024]; h_n [2,64,1024]; c_n [2,64,1024]
#define OUT_HN 33554432
#define OUT_CN (33554432 + 131072)

__device__ __forceinline__ unsigned short f2bf(float f) {
  unsigned u = __float_as_uint(f);
  return (unsigned short)((u + 0x7fffu + ((u >> 16) & 1u)) >> 16);
}
__device__ __forceinline__ float sigm(float v)  { return 1.f / (1.f + __expf(-v)); }
__device__ __forceinline__ float tanha(float v) { return 1.f - 2.f / (__expf(2.f * v) + 1.f); }

// agent-coherent (sc0 sc1) 8B load/store: bypass L1/L2, coherent at L3.
// No fences / buffer_inv / buffer_wbl2 anywhere in the steady state.
__device__ __forceinline__ u64 ld_h64(const u64* p) {
  return __hip_atomic_load(p, __ATOMIC_RELAXED, __HIP_MEMORY_SCOPE_AGENT);
}
__device__ __forceinline__ void st_h64(u64* p, u64 v) {
  __hip_atomic_store(p, v, __ATOMIC_RELAXED, __HIP_MEMORY_SCOPE_AGENT);
}

// x fp32 [B][S][I] -> bf16 time-major xb[s][b][i]
__global__ __launch_bounds__(256) void xconv(const float* __restrict__ x,
                                             unsigned short* __restrict__ xb) {
  const int idx = blockIdx.x * 256 + threadIdx.x;   // 0 .. 4M-1
  const int i4 = (idx & 127) * 4;
  const int b  = (idx >> 7) & 63;
  const int s  = idx >> 13;
  f32x4 v = *(const f32x4*)(x + ((size_t)b * NS + s) * NI + i4);
  u16x4 o;
  o[0] = f2bf(v[0]); o[1] = f2bf(v[1]); o[2] = f2bf(v[2]); o[3] = f2bf(v[3]);
  *(u16x4*)(xb + ((size_t)s * NB + b) * NI + i4) = o;
}

// One block per CU. Each block owns hidden units [4*cu, 4*cu+4) of BOTH layers.
// Phase t: layer0 computes step t, layer1 computes step t-1 -> 1 grid barrier/phase.
__global__ __launch_bounds__(512, 2) void lstm2(
    const float* __restrict__ x,
    const float* __restrict__ Wx0, const float* __restrict__ Wh0,
    const float* __restrict__ bx0, const float* __restrict__ bh0,
    const float* __restrict__ Wx1, const float* __restrict__ Wh1,
    const float* __restrict__ bx1, const float* __restrict__ bh1,
    float* __restrict__ out, char* __restrict__ ws,
    const unsigned short* __restrict__ xb)
{
  extern __shared__ char smem[];
  float* PB   = (float*)(smem + OFF_PB);
  float* BIAS = (float*)(smem + OFF_BIAS);

  const int tid = threadIdx.x;
  const int cu  = blockIdx.x;

  int* cnt = (int*)ws;
  u64* h0b0 = (u64*)(ws + WS_H0);
  u64* h0b1 = (u64*)(ws + WS_H0 + 131072);
  u64* h1b0 = (u64*)(ws + WS_H1);
  u64* h1b1 = (u64*)(ws + WS_H1 + 131072);

  // ---- one-time: stage this CU's weight slices into LDS as bf16 ----
  for (int idx = tid; idx < 16 * 1024; idx += 512) {
    const int s = idx >> 10, k = idx & 1023;            // s = gate*4 + unit
    const int j = (s >> 2) * 1024 + cu * 4 + (s & 3);   // global row in [4096]
    *(unsigned short*)(smem + OFF_WH0 + s * PW + 2 * k) = f2bf(Wh0[j * 1024 + k]);
    *(unsigned short*)(smem + OFF_WX1 + s * PW + 2 * k) = f2bf(Wx1[j * 1024 + k]);
    *(unsigned short*)(smem + OFF_WH1 + s * PW + 2 * k) = f2bf(Wh1[j * 1024 + k]);
  }
  for (int idx = tid; idx < 16 * 512; idx += 512) {
    const int s = idx >> 9, k = idx & 511;
    const int j = (s >> 2) * 1024 + cu * 4 + (s & 3);
    *(unsigned short*)(smem + OFF_WX0 + s * PW0 + 2 * k) = f2bf(Wx0[j * 512 + k]);
  }
  if (tid < 32) {
    const int L = tid >> 4, s = tid & 15;
    const int j = (s >> 2) * 1024 + cu * 4 + (s & 3);
    BIAS[tid] = (L == 0) ? (bx0[j] + bh0[j]) : (bx1[j] + bh1[j]);
  }
  __syncthreads();

  const int lane = tid & 63, wid = tid >> 6;
  const int m = wid & 3, role = wid >> 2;
  const int arow = lane & 15, agrp = lane >> 4;
  const int bcol = lane & 15;
  const int Ar = 16 * m + arow;
  const int bofsK = bcol * PW  + agrp * 16;
  const int bofs0 = bcol * PW0 + agrp * 16;
  const int aoff64 = Ar * 256 + agrp * 2;      // u64 index into h buffer rows

  const int eL = tid >> 8, eu = tid & 3, eb = (tid >> 2) & 63;
  const int erow = eb & 15, emt = eb >> 4;
  const int nglob = cu * 4 + eu;
  float cst = 0.f;
  int bar_dead = 0;

  union U16 { u64 q[2]; bf16x8 v; };

  for (int t = 0; t <= NS; ++t) {
    f32x4 c0 = {0.f, 0.f, 0.f, 0.f};
    f32x4 c1 = {0.f, 0.f, 0.f, 0.f};
    const u64* h0_rd = ((t & 1) == 0) ? h0b1 : h0b0;  // h0(t-1)
    const u64* h1_rd = (t & 1) ? h1b1 : h1b0;         // h1(t-2)

    if (role == 0) {
      const u64* ap  = h0_rd + aoff64;
      const char* b0p = smem + OFF_WH0 + bofsK;
      const char* b1p = smem + OFF_WX1 + bofsK;
#pragma unroll 8
      for (int ks = 0; ks < 32; ++ks) {
        U16 ua; ua.q[0] = ld_h64(ap + ks * 8); ua.q[1] = ld_h64(ap + ks * 8 + 1);
        bf16x8 w0 = *(const bf16x8*)(b0p + ks * 64);
        bf16x8 w1 = *(const bf16x8*)(b1p + ks * 64);
        c0 = __builtin_amdgcn_mfma_f32_16x16x32_bf16(ua.v, w0, c0, 0, 0, 0);
        c1 = __builtin_amdgcn_mfma_f32_16x16x32_bf16(ua.v, w1, c1, 0, 0, 0);
      }
    } else {
      if (t < NS) {
        const char* b0p = smem + OFF_WX0 + bofs0;
        if (xb) {
          const char* ap0 = (const char*)(xb + ((size_t)t * NB + Ar) * NI) + agrp * 16;
#pragma unroll 8
          for (int ks = 0; ks < 16; ++ks) {
            bf16x8 a  = *(const bf16x8*)(ap0 + ks * 64);
            bf16x8 w0 = *(const bf16x8*)(b0p + ks * 64);
            c0 = __builtin_amdgcn_mfma_f32_16x16x32_bf16(a, w0, c0, 0, 0, 0);
          }
        } else {
          const float* xp = x + ((size_t)Ar * NS + t) * NI + agrp * 8;
#pragma unroll 4
          for (int ks = 0; ks < 16; ++ks) {
            f32x4 f0 = *(const f32x4*)(xp + ks * 32);
            f32x4 f1 = *(const f32x4*)(xp + ks * 32 + 4);
            bf16x8 a;
            a[0] = (short)f2bf(f0[0]); a[1] = (short)f2bf(f0[1]);
            a[2] = (short)f2bf(f0[2]); a[3] = (short)f2bf(f0[3]);
            a[4] = (short)f2bf(f1[0]); a[5] = (short)f2bf(f1[1]);
            a[6] = (short)f2bf(f1[2]); a[7] = (short)f2bf(f1[3]);
            bf16x8 w0 = *(const bf16x8*)(b0p + ks * 64);
            c0 = __builtin_amdgcn_mfma_f32_16x16x32_bf16(a, w0, c0, 0, 0, 0);
          }
        }
      }
      const u64* ap  = h1_rd + aoff64;
      const char* b1p = smem + OFF_WH1 + bofsK;
#pragma unroll 8
      for (int ks = 0; ks < 32; ++ks) {
        U16 ua; ua.q[0] = ld_h64(ap + ks * 8); ua.q[1] = ld_h64(ap + ks * 8 + 1);
        bf16x8 w1 = *(const bf16x8*)(b1p + ks * 64);
        c1 = __builtin_amdgcn_mfma_f32_16x16x32_bf16(ua.v, w1, c1, 0, 0, 0);
      }
    }

    // dump partial tiles: D layout col=lane&15, row=(lane>>4)*4+r  [m89]
    {
      const int ti0 = ((m << 1) | role) << 1;
      float* p0 = PB + ti0 * 256;
      float* p1 = PB + (ti0 + 1) * 256;
      const int rb = agrp * 4;
#pragma unroll
      for (int r = 0; r < 4; ++r) {
        p0[(rb + r) * 16 + bcol] = c0[r];
        p1[(rb + r) * 16 + bcol] = c1[r];
      }
    }
    __syncthreads();

    const bool act = (eL == 0) ? (t < NS) : (t >= 1);
    if (act) {
      const int tiA = (emt << 2) | eL;
      const int tiB = (emt << 2) | 2 | eL;
      const float* pA = PB + tiA * 256 + erow * 16;
      const float* pB = PB + tiB * 256 + erow * 16;
      const float* bi = BIAS + eL * 16;
      float gi = pA[eu]      + pB[eu]      + bi[eu];
      float gf = pA[eu + 4]  + pB[eu + 4]  + bi[eu + 4];
      float go = pA[eu + 8]  + pB[eu + 8]  + bi[eu + 8];
      float gg = pA[eu + 12] + pB[eu + 12] + bi[eu + 12];
      float cn = sigm(gf) * cst + sigm(gi) * tanha(gg);
      float hn = sigm(go) * tanha(cn);
      cst = cn;

      // pack 4 units (4 adjacent lanes) -> one 8B agent-scope store
      const unsigned hv = (unsigned)f2bf(hn);
      const unsigned h2 = hv | (((unsigned)__shfl_xor((int)hv, 1)) << 16);
      const unsigned hi = (unsigned)__shfl_xor((int)h2, 2);
      u64* wr;
      if (eL == 0) wr = (t & 1) ? h0b1 : h0b0;     // h0(t) -> buf t&1
      else         wr = (t & 1) ? h1b0 : h1b1;     // h1(t-1) -> buf (t-1)&1
      if ((lane & 3) == 0)
        st_h64(wr + (eb * NH + cu * 4) / 4, (u64)h2 | ((u64)hi << 32));

      if (eL == 0) {
        if (t == NS - 1) {
          out[OUT_HN + eb * NH + nglob] = hn;
          out[OUT_CN + eb * NH + nglob] = cn;
        }
      } else {
        out[((size_t)eb * NS + (t - 1)) * NH + nglob] = hn;
        if (t == NS) {
          out[OUT_HN + 65536 + eb * NH + nglob] = hn;
          out[OUT_CN + 65536 + eb * NH + nglob] = cn;
        }
      }
    }

    if (t == NS) break;

    // ---- grid barrier: relaxed monotonic counter; no fences, no inv ----
    __syncthreads();   // drains each wave's vmcnt(0): h stores are at L3
    if (tid == 0) {
      __hip_atomic_fetch_add(cnt, 1, __ATOMIC_RELAXED, __HIP_MEMORY_SCOPE_AGENT);
      if (!bar_dead) {
        const int target = 256 * (t + 1);
        int spins = 0;
        while (__hip_atomic_load(cnt, __ATOMIC_RELAXED, __HIP_MEMORY_SCOPE_AGENT) < target) {
          __builtin_amdgcn_s_sleep(4);
          if (++spins > (1 << 20)) { bar_dead = 1; break; }
        }
      }
    }
    asm volatile("" ::: "memory");
    __syncthreads();
  }
}

extern "C" void kernel_launch(void* const* d_in, const int* in_sizes, int n_in,
                              void* d_out, int out_size, void* d_ws, size_t ws_size,
                              hipStream_t stream) {
  const float* x   = (const float*)d_in[0];
  const float* Wx0 = (const float*)d_in[1];
  const float* Wh0 = (const float*)d_in[2];
  const float* bx0 = (const float*)d_in[3];
  const float* bh0 = (const float*)d_in[4];
  const float* Wx1 = (const float*)d_in[5];
  const float* Wh1 = (const float*)d_in[6];
  const float* bx1 = (const float*)d_in[7];
  const float* bh1 = (const float*)d_in[8];
  float* out = (float*)d_out;
  char* ws = (char*)d_ws;

  const bool have_xb = ws_size >= (size_t)WS_XB_NEED;
  unsigned short* xbp = have_xb ? (unsigned short*)(ws + WS_XB) : nullptr;

  (void)hipFuncSetAttribute((const void*)lstm2,
                            hipFuncAttributeMaxDynamicSharedMemorySize, SMEM_BYTES);
  (void)hipMemsetAsync(ws, 0, WS_ZERO_BYTES, stream);  // zero barrier cnt + h ping-pong bufs
  if (have_xb)
    hipLaunchKernelGGL(xconv, dim3((NS * NB * NI / 4) / 256), dim3(256), 0, stream, x, xbp);
  hipLaunchKernelGGL(lstm2, dim3(256), dim3(512), SMEM_BYTES, stream,
                     x, Wx0, Wh0, bx0, bh0, Wx1, Wh1, bx1, bh1, out, ws, xbp);
}